// Round 8
// baseline (2684.948 us; speedup 1.0000x reference)
//
#include <hip/hip_runtime.h>
#include <hip/hip_bf16.h>

#define N_USERS 100000
#define E_HYPER 50000
#define NNZ_E   800000
#define T_STEPS 8
#define DIM     64
#define IDXM    0xFFFFF

#define TR_BLOCKS 1024
#define GE_BLOCKS 1563
#define GN_BLOCKS 3125
#define B_BLOCKS  3125
#define FU_BLOCKS 1024

typedef __bf16 bf16x8 __attribute__((ext_vector_type(8)));
typedef float  f32x4  __attribute__((ext_vector_type(4)));

// ---------------------------------------------------------------------------
__device__ __forceinline__ float ld_in(const void* p, size_t i, int f32)
{
    return f32 ? ((const float*)p)[i]
               : __bfloat162float(((const __hip_bfloat16*)p)[i]);
}

__device__ __forceinline__ int dec(int v, int tag)
{
    return ((v >> 20) == tag) ? (v & IDXM) : -1;
}

// carry access: f32-in-dout(f=1) | f32-in-ws | bf16-in-dout
__device__ __forceinline__ float ld_carry(void* out, float* cws, size_t i,
                                          int f, int use_ws)
{
    if (f) return ((float*)out)[i];
    if (use_ws) return cws[i];
    return __bfloat162float(((__hip_bfloat16*)out)[i]);
}
__device__ __forceinline__ void st_carry(void* out, float* cws, size_t i,
                                         int f, int use_ws, int wr, float v)
{
    if (f) { ((float*)out)[i] = v; return; }
    if (use_ws) {
        cws[i] = v;
        if (wr) ((__hip_bfloat16*)out)[i] = __float2bfloat16(v);
        return;
    }
    ((__hip_bfloat16*)out)[i] = __float2bfloat16(v);
}

// ---------------------------------------------------------------------------
// Kernel 0: input dtype detector (proven: resolves f=0 for bf16 inputs)
// ---------------------------------------------------------------------------
__global__ void k_detect(const unsigned short* __restrict__ raw, int* __restrict__ flag)
{
    __shared__ int cnt;
    if (threadIdx.x == 0) cnt = 0;
    __syncthreads();
    int c = 0;
    for (int i = threadIdx.x; i < 4096; i += blockDim.x) {
        int e = (raw[i] >> 7) & 0xFF;
        if (e > 126) c++;
    }
    atomicAdd(&cnt, c);
    __syncthreads();
    if (threadIdx.x == 0) *flag = (cnt > 64) ? 1 : 0;
}

// ---------------------------------------------------------------------------
// Kernel 0b: params -> fp32 staging
// st: W[0,4096) b[4096,4160) w1[4160,8256) b1[8256,8320) w2[8320,8384) b2[8384]
// ---------------------------------------------------------------------------
__global__ void k_convert_params(
    const void* W, const void* b, const void* w1, const void* b1,
    const void* w2, const void* b2, const int* __restrict__ flag,
    float* __restrict__ st)
{
    int f = *flag;
    int i = blockIdx.x * blockDim.x + threadIdx.x;
    if (i < 4096)          st[i] = ld_in(W,  i,        f);
    else if (i < 4160)     st[i] = ld_in(b,  i - 4096, f);
    else if (i < 8256)     st[i] = ld_in(w1, i - 4160, f);
    else if (i < 8320)     st[i] = ld_in(b1, i - 8256, f);
    else if (i < 8384)     st[i] = ld_in(w2, i - 8320, f);
    else if (i == 8384)    st[i] = ld_in(b2, 0,        f);
}

// ---------------------------------------------------------------------------
// task bodies
// ---------------------------------------------------------------------------
__device__ __forceinline__ void build_body(
    const int* __restrict__ nodes, const int* __restrict__ hyper,
    int* __restrict__ he, int* __restrict__ ne,
    int* __restrict__ hn, int* __restrict__ nn, int tag, int i)
{
    if (i >= NNZ_E) return;
    int tv = (tag << 20) | i;
    ne[i] = atomicExch(&he[hyper[i]], tv);
    nn[i] = atomicExch(&hn[nodes[i]], tv);
}

__device__ __forceinline__ void ge_body(
    const __hip_bfloat16* __restrict__ h, const int* __restrict__ nodes,
    const int* __restrict__ he, const int* __restrict__ ne,
    __hip_bfloat16* __restrict__ e, int tag, int bid, int nblocks, int tid)
{
    int lane = tid & 63;
    int wid = bid * 4 + (tid >> 6);
    int nW  = nblocks * 4;
    for (int s0 = wid * 8; s0 < E_HYPER; s0 += nW * 8) {
        int idx[8]; float acc[8]; int cnt[8];
#pragma unroll
        for (int c = 0; c < 8; ++c) {
            int sg = s0 + c;
            idx[c] = (sg < E_HYPER) ? dec(he[sg], tag) : -1;
            acc[c] = 0.f; cnt[c] = 0;
        }
        while (true) {
            bool any = false;
#pragma unroll
            for (int c = 0; c < 8; ++c) any = any || (idx[c] >= 0);
            if (!any) break;
            int nxt[8], nd[8];
#pragma unroll
            for (int c = 0; c < 8; ++c)
                if (idx[c] >= 0) { nxt[c] = ne[idx[c]]; nd[c] = nodes[idx[c]]; }
#pragma unroll
            for (int c = 0; c < 8; ++c)
                if (idx[c] >= 0) {
                    acc[c] += __bfloat162float(h[(size_t)nd[c] * DIM + lane]);
                    cnt[c]++; idx[c] = dec(nxt[c], tag);
                }
        }
#pragma unroll
        for (int c = 0; c < 8; ++c) {
            int sg = s0 + c;
            if (sg < E_HYPER)
                e[(size_t)sg * DIM + lane] =
                    __float2bfloat16(acc[c] / (float)max(cnt[c], 1));
        }
    }
}

__device__ __forceinline__ void gn_body(
    const __hip_bfloat16* __restrict__ e, const int* __restrict__ hyper,
    const int* __restrict__ hn, const int* __restrict__ nn,
    __hip_bfloat16* __restrict__ dyb, void* __restrict__ dout,
    float* __restrict__ cws, int f, int use_ws, int to_carry, int tag,
    int bid, int nblocks, int tid)
{
    int lane = tid & 63;
    int wid = bid * 4 + (tid >> 6);
    int nW  = nblocks * 4;
    for (int s0 = wid * 8; s0 < N_USERS; s0 += nW * 8) {
        int idx[8]; float acc[8]; int cnt[8];
#pragma unroll
        for (int c = 0; c < 8; ++c) {
            int sg = s0 + c;
            idx[c] = (sg < N_USERS) ? dec(hn[sg], tag) : -1;
            acc[c] = 0.f; cnt[c] = 0;
        }
        while (true) {
            bool any = false;
#pragma unroll
            for (int c = 0; c < 8; ++c) any = any || (idx[c] >= 0);
            if (!any) break;
            int nxt[8], hy[8];
#pragma unroll
            for (int c = 0; c < 8; ++c)
                if (idx[c] >= 0) { nxt[c] = nn[idx[c]]; hy[c] = hyper[idx[c]]; }
#pragma unroll
            for (int c = 0; c < 8; ++c)
                if (idx[c] >= 0) {
                    acc[c] += __bfloat162float(e[(size_t)hy[c] * DIM + lane]);
                    cnt[c]++; idx[c] = dec(nxt[c], tag);
                }
        }
#pragma unroll
        for (int c = 0; c < 8; ++c) {
            int sg = s0 + c;
            if (sg < N_USERS) {
                float v = acc[c] / (float)max(cnt[c], 1);
                size_t o = (size_t)sg * DIM + lane;
                if (to_carry) st_carry(dout, cws, o, f, use_ws, 0, v);
                else          dyb[o] = __float2bfloat16(v);
            }
        }
    }
}

// fuse: carry = softmax-blend(carry, dy) via MFMA 16x16x32 bf16 (R5-proven
// fragment layout). dy is bf16 (blend error ~1e-4/step, within budget).
__device__ __forceinline__ void fu_body(
    void* __restrict__ dout, float* __restrict__ cws,
    const __hip_bfloat16* __restrict__ dyb, const float* __restrict__ st,
    int f, int use_ws, int write_out, int bid, int nblocks, int tid)
{
    float* cf = f ? (float*)dout : (use_ws ? cws : (float*)0);
    __hip_bfloat16* cb = (__hip_bfloat16*)dout;

    int lane = tid & 63;
    int quad = lane >> 4;
    int m    = lane & 15;

    bf16x8 bw[4][2];
    float b1v[4], w2v[4];
#pragma unroll
    for (int nt = 0; nt < 4; ++nt) {
#pragma unroll
        for (int kb = 0; kb < 2; ++kb)
#pragma unroll
            for (int j = 0; j < 8; ++j) {
                int k = kb * 32 + quad * 8 + j;
                bw[nt][kb][j] = (__bf16)st[4160 + k * 64 + nt * 16 + m];
            }
        b1v[nt] = st[8256 + nt * 16 + m];
        w2v[nt] = st[8320 + nt * 16 + m];
    }

    int wid = bid * 4 + (tid >> 6);
    int nW  = nblocks * 4;
    const int NT = N_USERS / 16;

    for (int tile = wid; tile < NT; tile += nW) {
        int row = tile * 16 + m;
        size_t base = (size_t)row * DIM;

        float hidf[2][8], dyf[2][8];
        bf16x8 ah[2], ad[2];
#pragma unroll
        for (int kb = 0; kb < 2; ++kb) {
            ad[kb] = *(const bf16x8*)(const void*)(dyb + base + kb * 32 + quad * 8);
#pragma unroll
            for (int j = 0; j < 8; ++j) dyf[kb][j] = (float)ad[kb][j];
            if (cf) {
                const f32x4* cp = (const f32x4*)(cf + base);
                f32x4 a = cp[kb * 8 + quad * 2], b = cp[kb * 8 + quad * 2 + 1];
#pragma unroll
                for (int j = 0; j < 4; ++j) {
                    hidf[kb][j] = a[j]; hidf[kb][4 + j] = b[j];
                }
#pragma unroll
                for (int j = 0; j < 8; ++j) ah[kb][j] = (__bf16)hidf[kb][j];
            } else {
                bf16x8 hv = *(const bf16x8*)(const void*)(cb + base + kb * 32 + quad * 8);
                ah[kb] = hv;
#pragma unroll
                for (int j = 0; j < 8; ++j) hidf[kb][j] = (float)hv[j];
            }
        }

        float zh[4] = {0.f, 0.f, 0.f, 0.f};
        float zd[4] = {0.f, 0.f, 0.f, 0.f};
#pragma unroll
        for (int nt = 0; nt < 4; ++nt) {
            f32x4 acch = {0.f, 0.f, 0.f, 0.f};
            f32x4 accd = {0.f, 0.f, 0.f, 0.f};
#pragma unroll
            for (int kb = 0; kb < 2; ++kb) {
                acch = __builtin_amdgcn_mfma_f32_16x16x32_bf16(ah[kb], bw[nt][kb], acch, 0, 0, 0);
                accd = __builtin_amdgcn_mfma_f32_16x16x32_bf16(ad[kb], bw[nt][kb], accd, 0, 0, 0);
            }
#pragma unroll
            for (int reg = 0; reg < 4; ++reg) {
                zh[reg] += tanhf(acch[reg] + b1v[nt]) * w2v[nt];
                zd[reg] += tanhf(accd[reg] + b1v[nt]) * w2v[nt];
            }
        }
        float s[4];
#pragma unroll
        for (int reg = 0; reg < 4; ++reg) {
#pragma unroll
            for (int off = 1; off < 16; off <<= 1) {
                zh[reg] += __shfl_xor(zh[reg], off, 64);
                zd[reg] += __shfl_xor(zd[reg], off, 64);
            }
            float mm = fmaxf(zh[reg], zd[reg]);
            float eh = expf(zh[reg] - mm), ed = expf(zd[reg] - mm);
            s[reg] = eh / (eh + ed);
        }
        int srcl = (m >> 2) * 16;
        float s0 = __shfl(s[0], srcl, 64), s1 = __shfl(s[1], srcl, 64);
        float s2 = __shfl(s[2], srcl, 64), s3 = __shfl(s[3], srcl, 64);
        int r3 = m & 3;
        float sv = (r3 == 0) ? s0 : (r3 == 1) ? s1 : (r3 == 2) ? s2 : s3;

        if (cf) {
            f32x4* cp = (f32x4*)(cf + base);
#pragma unroll
            for (int kb = 0; kb < 2; ++kb) {
                f32x4 v0, v1;
#pragma unroll
                for (int j = 0; j < 4; ++j) {
                    v0[j] = sv * hidf[kb][j]     + (1.f - sv) * dyf[kb][j];
                    v1[j] = sv * hidf[kb][4 + j] + (1.f - sv) * dyf[kb][4 + j];
                }
                cp[kb * 8 + quad * 2]     = v0;
                cp[kb * 8 + quad * 2 + 1] = v1;
                if (write_out && !f) {
#pragma unroll
                    for (int j = 0; j < 4; ++j) {
                        int k = kb * 32 + quad * 8 + j;
                        cb[base + k]     = __float2bfloat16(v0[j]);
                        cb[base + k + 4] = __float2bfloat16(v1[j]);
                    }
                }
            }
        } else {
#pragma unroll
            for (int kb = 0; kb < 2; ++kb)
#pragma unroll
                for (int j = 0; j < 8; ++j) {
                    int k = kb * 32 + quad * 8 + j;
                    float v = sv * hidf[kb][j] + (1.f - sv) * dyf[kb][j];
                    cb[base + k] = __float2bfloat16(v);
                }
        }
    }
}

// ---------------------------------------------------------------------------
// merged kernels
// ---------------------------------------------------------------------------
__global__ __launch_bounds__(256) void k_trans_build(
    const void* __restrict__ emb, const int* __restrict__ flag,
    const float* __restrict__ st, __hip_bfloat16* __restrict__ h,
    const int* __restrict__ nodes, const int* __restrict__ hyper,
    int* __restrict__ he, int* __restrict__ ne,
    int* __restrict__ hn, int* __restrict__ nn, int tag)
{
    __shared__ float Wl[DIM * DIM];
    __shared__ float bl[DIM];
    if ((int)blockIdx.x < TR_BLOCKS) {
        for (int i = threadIdx.x; i < DIM * DIM; i += blockDim.x) Wl[i] = st[i];
        if (threadIdx.x < DIM) bl[threadIdx.x] = st[4096 + threadIdx.x];
        __syncthreads();
        int f = *flag;
        int wave = threadIdx.x >> 6, lane = threadIdx.x & 63;
        int nW = TR_BLOCKS * 4;
        for (int row = blockIdx.x * 4 + wave; row < N_USERS; row += nW) {
            size_t base = (size_t)row * DIM;
            float v = ld_in(emb, base + lane, f);
            float acc = bl[lane];
#pragma unroll
            for (int k = 0; k < DIM; ++k)
                acc += __shfl(v, k, 64) * Wl[k * DIM + lane];
            h[base + lane] = __float2bfloat16(fmaxf(acc, 0.f));
        }
    } else {
        int i = (blockIdx.x - TR_BLOCKS) * blockDim.x + threadIdx.x;
        build_body(nodes, hyper, he, ne, hn, nn, tag, i);
    }
}

__global__ __launch_bounds__(256) void k_ge_fuse(
    const __hip_bfloat16* __restrict__ h, const int* __restrict__ nodes,
    const int* __restrict__ he, const int* __restrict__ ne,
    __hip_bfloat16* __restrict__ e, int tag, int ge_blocks,
    void* __restrict__ dout, float* __restrict__ cws,
    const __hip_bfloat16* __restrict__ dyb, const float* __restrict__ st,
    const int* __restrict__ flag, int use_ws, int do_fuse, int write_out)
{
    if ((int)blockIdx.x < ge_blocks) {
        ge_body(h, nodes, he, ne, e, tag, blockIdx.x, ge_blocks, threadIdx.x);
    } else if (do_fuse) {
        fu_body(dout, cws, dyb, st, *flag, use_ws, write_out,
                blockIdx.x - ge_blocks, gridDim.x - ge_blocks, threadIdx.x);
    }
}

__global__ __launch_bounds__(256) void k_gn_build(
    const __hip_bfloat16* __restrict__ e, const int* __restrict__ hyper,
    const int* __restrict__ hn, const int* __restrict__ nn,
    __hip_bfloat16* __restrict__ dyb, void* __restrict__ dout,
    float* __restrict__ cws, const int* __restrict__ flag,
    int use_ws, int to_carry, int tag, int gn_blocks,
    const int* __restrict__ nodes1, const int* __restrict__ hyper1,
    int* __restrict__ he1, int* __restrict__ ne1,
    int* __restrict__ hn1, int* __restrict__ nn1, int tag1, int do_build)
{
    if ((int)blockIdx.x < gn_blocks) {
        gn_body(e, hyper, hn, nn, dyb, dout, cws, *flag, use_ws, to_carry,
                tag, blockIdx.x, gn_blocks, threadIdx.x);
    } else if (do_build) {
        int i = (blockIdx.x - gn_blocks) * blockDim.x + threadIdx.x;
        build_body(nodes1, hyper1, he1, ne1, hn1, nn1, tag1, i);
    }
}

// ---------------------------------------------------------------------------
extern "C" void kernel_launch(void* const* d_in, const int* in_sizes, int n_in,
                              void* d_out, int out_size, void* d_ws,
                              size_t ws_size, hipStream_t stream)
{
    const void* user_emb = d_in[0];
    const void* W_conv   = d_in[1];
    const void* b_conv   = d_in[2];
    const void* fus_w1   = d_in[3];
    const void* fus_b1   = d_in[4];
    const void* fus_w2   = d_in[5];
    const void* fus_b2   = d_in[6];
    const int* edge_nodes = (const int*)d_in[7];
    const int* edge_hyper = (const int*)d_in[8];

    const size_t ND = (size_t)N_USERS * DIM;

    // ws layout (fp32 word offsets), base = 46.03 MB:
    //   0        : flag
    //   16       : st [8448]
    //   8464     : he0[50000]   58464: he1[50000]
    //   108464   : hn0[100000] 208464: hn1[100000]
    //   308464   : ne0[800000] 1108464: ne1[800000]
    //   1908464  : nn0[800000] 2708464: nn1[800000]
    //   3508464  : e bf16 [E*D]    (1.6M words)
    //   5108464  : dy bf16 [N*D]   (3.2M words)
    //   8308464  : h bf16 [N*D]    (3.2M words)
    //   11508464 : optional fp32 carry [N*D] -> 71.63 MB
    float* ws = (float*)d_ws;
    int*   flag = (int*)ws;
    float* st   = ws + 16;
    int* he[2] = {(int*)(ws + 8464),    (int*)(ws + 58464)};
    int* hn[2] = {(int*)(ws + 108464),  (int*)(ws + 208464)};
    int* ne[2] = {(int*)(ws + 308464),  (int*)(ws + 1108464)};
    int* nn[2] = {(int*)(ws + 1908464), (int*)(ws + 2708464)};
    __hip_bfloat16* e_buf = (__hip_bfloat16*)(ws + 3508464);
    __hip_bfloat16* dyb   = (__hip_bfloat16*)(ws + 5108464);
    __hip_bfloat16* h     = (__hip_bfloat16*)(ws + 8308464);
    float* carry_ws       = ws + 11508464;

    const size_t need_ws_carry = (11508464 + ND) * 4;
    const int use_ws = (ws_size >= need_ws_carry) ? 1 : 0;

    k_detect<<<1, 256, 0, stream>>>((const unsigned short*)user_emb, flag);
    k_convert_params<<<(8385 + 255) / 256, 256, 0, stream>>>(
        W_conv, b_conv, fus_w1, fus_b1, fus_w2, fus_b2, flag, st);

    // prologue: transform || build(0) into buffer 0
    k_trans_build<<<TR_BLOCKS + B_BLOCKS, 256, 0, stream>>>(
        user_emb, flag, st, h, edge_nodes, edge_hyper,
        he[0], ne[0], hn[0], nn[0], 1);

    for (int t = 0; t < T_STEPS; ++t) {
        int b  = t & 1;
        int nb = b ^ 1;
        const int* nodes  = edge_nodes + (size_t)t * NNZ_E;
        const int* hyper  = edge_hyper + (size_t)t * NNZ_E;
        const int* nodes1 = edge_nodes + (size_t)(t + 1) * NNZ_E;
        const int* hyper1 = edge_hyper + (size_t)(t + 1) * NNZ_E;

        // gather_e(t) || fuse(t-1)
        int gridA = GE_BLOCKS + ((t > 0) ? FU_BLOCKS : 0);
        k_ge_fuse<<<gridA, 256, 0, stream>>>(
            h, nodes, he[b], ne[b], e_buf, t + 1, GE_BLOCKS,
            d_out, carry_ws, dyb, st, flag, use_ws, (t > 0) ? 1 : 0, 0);

        // gather_n(t) || build(t+1)
        int do_b = (t < T_STEPS - 1) ? 1 : 0;
        int gridB = GN_BLOCKS + (do_b ? B_BLOCKS : 0);
        k_gn_build<<<gridB, 256, 0, stream>>>(
            e_buf, hyper, hn[b], nn[b], dyb, d_out, carry_ws, flag,
            use_ws, (t == 0) ? 1 : 0, t + 1, GN_BLOCKS,
            do_b ? nodes1 : nodes, do_b ? hyper1 : hyper,
            he[nb], ne[nb], hn[nb], nn[nb], t + 2, do_b);
    }

    // epilogue: fuse(7) with final bf16 output write
    k_ge_fuse<<<FU_BLOCKS, 256, 0, stream>>>(
        h, edge_nodes, he[1], ne[1], e_buf, 8, 0,
        d_out, carry_ws, dyb, st, flag, use_ws, 1, 1);
}

// Round 9
// 1975.931 us; speedup vs baseline: 1.3588x; 1.3588x over previous
//
#include <hip/hip_runtime.h>
#include <hip/hip_bf16.h>

#define N_USERS 100000
#define E_HYPER 50000
#define NNZ_E   800000
#define T_STEPS 8
#define DIM     64
#define IDXM    0xFFFFF

#define TR_BLOCKS 1024
#define GE_BLOCKS 1563
#define GN_BLOCKS 3125
#define B_BLOCKS  3125
#define FU_BLOCKS 1024

typedef __bf16 bf16x8 __attribute__((ext_vector_type(8)));
typedef float  f32x4  __attribute__((ext_vector_type(4)));

// ---------------------------------------------------------------------------
__device__ __forceinline__ float ld_in(const void* p, size_t i, int f32)
{
    return f32 ? ((const float*)p)[i]
               : __bfloat162float(((const __hip_bfloat16*)p)[i]);
}

__device__ __forceinline__ int dec(int v, int tag)
{
    return ((v >> 20) == tag) ? (v & IDXM) : -1;
}

// carry access: f32-in-dout(f=1) | f32-in-ws | bf16-in-dout
__device__ __forceinline__ float ld_carry(void* out, float* cws, size_t i,
                                          int f, int use_ws)
{
    if (f) return ((float*)out)[i];
    if (use_ws) return cws[i];
    return __bfloat162float(((__hip_bfloat16*)out)[i]);
}
__device__ __forceinline__ void st_carry(void* out, float* cws, size_t i,
                                         int f, int use_ws, int wr, float v)
{
    if (f) { ((float*)out)[i] = v; return; }
    if (use_ws) {
        cws[i] = v;
        if (wr) ((__hip_bfloat16*)out)[i] = __float2bfloat16(v);
        return;
    }
    ((__hip_bfloat16*)out)[i] = __float2bfloat16(v);
}

// ---------------------------------------------------------------------------
// Kernel 0: input dtype detector (proven: resolves f=0 for bf16 inputs)
// ---------------------------------------------------------------------------
__global__ void k_detect(const unsigned short* __restrict__ raw, int* __restrict__ flag)
{
    __shared__ int cnt;
    if (threadIdx.x == 0) cnt = 0;
    __syncthreads();
    int c = 0;
    for (int i = threadIdx.x; i < 4096; i += blockDim.x) {
        int e = (raw[i] >> 7) & 0xFF;
        if (e > 126) c++;
    }
    atomicAdd(&cnt, c);
    __syncthreads();
    if (threadIdx.x == 0) *flag = (cnt > 64) ? 1 : 0;
}

// ---------------------------------------------------------------------------
// Kernel 0b: params -> fp32 staging
// st: W[0,4096) b[4096,4160) w1[4160,8256) b1[8256,8320) w2[8320,8384) b2[8384]
// ---------------------------------------------------------------------------
__global__ void k_convert_params(
    const void* W, const void* b, const void* w1, const void* b1,
    const void* w2, const void* b2, const int* __restrict__ flag,
    float* __restrict__ st)
{
    int f = *flag;
    int i = blockIdx.x * blockDim.x + threadIdx.x;
    if (i < 4096)          st[i] = ld_in(W,  i,        f);
    else if (i < 4160)     st[i] = ld_in(b,  i - 4096, f);
    else if (i < 8256)     st[i] = ld_in(w1, i - 4160, f);
    else if (i < 8320)     st[i] = ld_in(b1, i - 8256, f);
    else if (i < 8384)     st[i] = ld_in(w2, i - 8320, f);
    else if (i == 8384)    st[i] = ld_in(b2, 0,        f);
}

// ---------------------------------------------------------------------------
// build body: tagged linked lists. head value = (tag<<20)|i.
// ---------------------------------------------------------------------------
__device__ __forceinline__ void build_body(
    const int* __restrict__ nodes, const int* __restrict__ hyper,
    int* __restrict__ he, int* __restrict__ ne,
    int* __restrict__ hn, int* __restrict__ nn, int tag, int i)
{
    if (i >= NNZ_E) return;
    int tv = (tag << 20) | i;
    ne[i] = atomicExch(&he[hyper[i]], tv);
    nn[i] = atomicExch(&hn[nodes[i]], tv);
}

// ---------------------------------------------------------------------------
// fuse body: carry = softmax-blend(carry, dy) via MFMA 16x16x32 bf16
// (R5/R7-proven fragment layout; b2 cancels in 2-way softmax)
// ---------------------------------------------------------------------------
__device__ __forceinline__ void fu_body(
    void* __restrict__ dout, float* __restrict__ cws,
    const float* __restrict__ dy_buf, const float* __restrict__ st,
    int f, int use_ws, int write_out, int bid, int nblocks, int tid)
{
    float* cf = f ? (float*)dout : (use_ws ? cws : (float*)0);
    __hip_bfloat16* cb = (__hip_bfloat16*)dout;

    int lane = tid & 63;
    int quad = lane >> 4;
    int m    = lane & 15;

    bf16x8 bw[4][2];
    float b1v[4], w2v[4];
#pragma unroll
    for (int nt = 0; nt < 4; ++nt) {
#pragma unroll
        for (int kb = 0; kb < 2; ++kb)
#pragma unroll
            for (int j = 0; j < 8; ++j) {
                int k = kb * 32 + quad * 8 + j;
                bw[nt][kb][j] = (__bf16)st[4160 + k * 64 + nt * 16 + m];
            }
        b1v[nt] = st[8256 + nt * 16 + m];
        w2v[nt] = st[8320 + nt * 16 + m];
    }

    int wid = bid * 4 + (tid >> 6);
    int nW  = nblocks * 4;
    const int NT = N_USERS / 16;

    for (int tile = wid; tile < NT; tile += nW) {
        int row = tile * 16 + m;
        size_t base = (size_t)row * DIM;

        float hidf[2][8], dyf[2][8];
        if (cf) {
            const f32x4* cp = (const f32x4*)(cf + base);
            const f32x4* dp = (const f32x4*)(dy_buf + base);
#pragma unroll
            for (int kb = 0; kb < 2; ++kb) {
                f32x4 a = cp[kb * 8 + quad * 2], b = cp[kb * 8 + quad * 2 + 1];
                f32x4 c = dp[kb * 8 + quad * 2], d = dp[kb * 8 + quad * 2 + 1];
#pragma unroll
                for (int j = 0; j < 4; ++j) {
                    hidf[kb][j] = a[j]; hidf[kb][4 + j] = b[j];
                    dyf[kb][j]  = c[j]; dyf[kb][4 + j]  = d[j];
                }
            }
        } else {
#pragma unroll
            for (int kb = 0; kb < 2; ++kb)
#pragma unroll
                for (int j = 0; j < 8; ++j) {
                    int k = kb * 32 + quad * 8 + j;
                    hidf[kb][j] = __bfloat162float(cb[base + k]);
                    dyf[kb][j]  = dy_buf[base + k];
                }
        }

        bf16x8 ah[2], ad[2];
#pragma unroll
        for (int kb = 0; kb < 2; ++kb)
#pragma unroll
            for (int j = 0; j < 8; ++j) {
                ah[kb][j] = (__bf16)hidf[kb][j];
                ad[kb][j] = (__bf16)dyf[kb][j];
            }

        float zh[4] = {0.f, 0.f, 0.f, 0.f};
        float zd[4] = {0.f, 0.f, 0.f, 0.f};
#pragma unroll
        for (int nt = 0; nt < 4; ++nt) {
            f32x4 acch = {0.f, 0.f, 0.f, 0.f};
            f32x4 accd = {0.f, 0.f, 0.f, 0.f};
#pragma unroll
            for (int kb = 0; kb < 2; ++kb) {
                acch = __builtin_amdgcn_mfma_f32_16x16x32_bf16(ah[kb], bw[nt][kb], acch, 0, 0, 0);
                accd = __builtin_amdgcn_mfma_f32_16x16x32_bf16(ad[kb], bw[nt][kb], accd, 0, 0, 0);
            }
#pragma unroll
            for (int reg = 0; reg < 4; ++reg) {
                zh[reg] += tanhf(acch[reg] + b1v[nt]) * w2v[nt];
                zd[reg] += tanhf(accd[reg] + b1v[nt]) * w2v[nt];
            }
        }
        float s[4];
#pragma unroll
        for (int reg = 0; reg < 4; ++reg) {
#pragma unroll
            for (int off = 1; off < 16; off <<= 1) {
                zh[reg] += __shfl_xor(zh[reg], off, 64);
                zd[reg] += __shfl_xor(zd[reg], off, 64);
            }
            float mm = fmaxf(zh[reg], zd[reg]);
            float eh = expf(zh[reg] - mm), ed = expf(zd[reg] - mm);
            s[reg] = eh / (eh + ed);
        }
        int srcl = (m >> 2) * 16;
        float s0 = __shfl(s[0], srcl, 64), s1 = __shfl(s[1], srcl, 64);
        float s2 = __shfl(s[2], srcl, 64), s3 = __shfl(s[3], srcl, 64);
        int r3 = m & 3;
        float sv = (r3 == 0) ? s0 : (r3 == 1) ? s1 : (r3 == 2) ? s2 : s3;

        if (cf) {
            f32x4* cp = (f32x4*)(cf + base);
#pragma unroll
            for (int kb = 0; kb < 2; ++kb) {
                f32x4 v0, v1;
#pragma unroll
                for (int j = 0; j < 4; ++j) {
                    v0[j] = sv * hidf[kb][j]     + (1.f - sv) * dyf[kb][j];
                    v1[j] = sv * hidf[kb][4 + j] + (1.f - sv) * dyf[kb][4 + j];
                }
                cp[kb * 8 + quad * 2]     = v0;
                cp[kb * 8 + quad * 2 + 1] = v1;
                if (write_out && !f) {
#pragma unroll
                    for (int j = 0; j < 4; ++j) {
                        int k = kb * 32 + quad * 8 + j;
                        cb[base + k]     = __float2bfloat16(v0[j]);
                        cb[base + k + 4] = __float2bfloat16(v1[j]);
                    }
                }
            }
        } else {
#pragma unroll
            for (int kb = 0; kb < 2; ++kb)
#pragma unroll
                for (int j = 0; j < 8; ++j) {
                    int k = kb * 32 + quad * 8 + j;
                    float v = sv * hidf[kb][j] + (1.f - sv) * dyf[kb][j];
                    cb[base + k] = __float2bfloat16(v);
                }
        }
    }
}

// ---------------------------------------------------------------------------
// Kernel A: transform || build(0)   (proven in R8)
// ---------------------------------------------------------------------------
__global__ __launch_bounds__(256) void k_trans_build(
    const void* __restrict__ emb, const int* __restrict__ flag,
    const float* __restrict__ st, __hip_bfloat16* __restrict__ h,
    const int* __restrict__ nodes, const int* __restrict__ hyper,
    int* __restrict__ he, int* __restrict__ ne,
    int* __restrict__ hn, int* __restrict__ nn, int tag)
{
    __shared__ float Wl[DIM * DIM];
    __shared__ float bl[DIM];
    if ((int)blockIdx.x < TR_BLOCKS) {
        for (int i = threadIdx.x; i < DIM * DIM; i += blockDim.x) Wl[i] = st[i];
        if (threadIdx.x < DIM) bl[threadIdx.x] = st[4096 + threadIdx.x];
        __syncthreads();
        int f = *flag;
        int wave = threadIdx.x >> 6, lane = threadIdx.x & 63;
        int nW = TR_BLOCKS * 4;
        for (int row = blockIdx.x * 4 + wave; row < N_USERS; row += nW) {
            size_t base = (size_t)row * DIM;
            float v = ld_in(emb, base + lane, f);
            float acc = bl[lane];
#pragma unroll
            for (int k = 0; k < DIM; ++k)
                acc += __shfl(v, k, 64) * Wl[k * DIM + lane];
            h[base + lane] = __float2bfloat16(fmaxf(acc, 0.f));
        }
    } else {
        int i = (blockIdx.x - TR_BLOCKS) * blockDim.x + threadIdx.x;
        build_body(nodes, hyper, he, ne, hn, nn, tag, i);
    }
}

// ---------------------------------------------------------------------------
// Kernel B: gather_e — pure, lean (R7 verbatim): 8 chains/wave
// ---------------------------------------------------------------------------
__global__ __launch_bounds__(256) void k_gather_e(
    const __hip_bfloat16* __restrict__ h,
    const int* __restrict__ nodes,
    const int* __restrict__ he, const int* __restrict__ ne,
    __hip_bfloat16* __restrict__ e, int tag)
{
    int lane = threadIdx.x & 63;
    int wid = blockIdx.x * (blockDim.x >> 6) + (threadIdx.x >> 6);
    int nW  = gridDim.x * (blockDim.x >> 6);
    for (int s0 = wid * 8; s0 < E_HYPER; s0 += nW * 8) {
        int idx[8]; float acc[8]; int cnt[8];
#pragma unroll
        for (int c = 0; c < 8; ++c) {
            int sg = s0 + c;
            idx[c] = (sg < E_HYPER) ? dec(he[sg], tag) : -1;
            acc[c] = 0.f; cnt[c] = 0;
        }
        while (true) {
            bool any = false;
#pragma unroll
            for (int c = 0; c < 8; ++c) any = any || (idx[c] >= 0);
            if (!any) break;
            int nxt[8], nd[8];
#pragma unroll
            for (int c = 0; c < 8; ++c)
                if (idx[c] >= 0) { nxt[c] = ne[idx[c]]; nd[c] = nodes[idx[c]]; }
#pragma unroll
            for (int c = 0; c < 8; ++c)
                if (idx[c] >= 0) {
                    acc[c] += __bfloat162float(h[(size_t)nd[c] * DIM + lane]);
                    cnt[c]++; idx[c] = dec(nxt[c], tag);
                }
        }
#pragma unroll
        for (int c = 0; c < 8; ++c) {
            int sg = s0 + c;
            if (sg < E_HYPER)
                e[(size_t)sg * DIM + lane] =
                    __float2bfloat16(acc[c] / (float)max(cnt[c], 1));
        }
    }
}

// ---------------------------------------------------------------------------
// Kernel C: gather_n — pure, lean (R7 verbatim): 8 chains/wave, fp32 dy
// ---------------------------------------------------------------------------
__global__ __launch_bounds__(256) void k_gather_n(
    const __hip_bfloat16* __restrict__ e,
    const int* __restrict__ hyper,
    const int* __restrict__ hn, const int* __restrict__ nn,
    float* __restrict__ dy,
    void* __restrict__ out, float* __restrict__ cws,
    const int* __restrict__ flag, int use_ws, int to_carry, int tag)
{
    int f = *flag;
    int lane = threadIdx.x & 63;
    int wid = blockIdx.x * (blockDim.x >> 6) + (threadIdx.x >> 6);
    int nW  = gridDim.x * (blockDim.x >> 6);
    for (int s0 = wid * 8; s0 < N_USERS; s0 += nW * 8) {
        int idx[8]; float acc[8]; int cnt[8];
#pragma unroll
        for (int c = 0; c < 8; ++c) {
            int sg = s0 + c;
            idx[c] = (sg < N_USERS) ? dec(hn[sg], tag) : -1;
            acc[c] = 0.f; cnt[c] = 0;
        }
        while (true) {
            bool any = false;
#pragma unroll
            for (int c = 0; c < 8; ++c) any = any || (idx[c] >= 0);
            if (!any) break;
            int nxt[8], hy[8];
#pragma unroll
            for (int c = 0; c < 8; ++c)
                if (idx[c] >= 0) { nxt[c] = nn[idx[c]]; hy[c] = hyper[idx[c]]; }
#pragma unroll
            for (int c = 0; c < 8; ++c)
                if (idx[c] >= 0) {
                    acc[c] += __bfloat162float(e[(size_t)hy[c] * DIM + lane]);
                    cnt[c]++; idx[c] = dec(nxt[c], tag);
                }
        }
#pragma unroll
        for (int c = 0; c < 8; ++c) {
            int sg = s0 + c;
            if (sg < N_USERS) {
                float v = acc[c] / (float)max(cnt[c], 1);
                size_t o = (size_t)sg * DIM + lane;
                if (to_carry) st_carry(out, cws, o, f, use_ws, 0, v);
                else          dy[o] = v;
            }
        }
    }
}

// ---------------------------------------------------------------------------
// Kernel D: build(t+1) || fuse(t) — both cache-reuse-free (safe merge)
// ---------------------------------------------------------------------------
__global__ __launch_bounds__(256) void k_build_fuse(
    const int* __restrict__ nodes1, const int* __restrict__ hyper1,
    int* __restrict__ he, int* __restrict__ ne,
    int* __restrict__ hn, int* __restrict__ nn, int tag1, int nbuild,
    void* __restrict__ dout, float* __restrict__ cws,
    const float* __restrict__ dy_buf, const float* __restrict__ st,
    const int* __restrict__ flag, int use_ws, int do_fuse, int write_out)
{
    if ((int)blockIdx.x < nbuild) {
        int i = blockIdx.x * blockDim.x + threadIdx.x;
        build_body(nodes1, hyper1, he, ne, hn, nn, tag1, i);
    } else if (do_fuse) {
        fu_body(dout, cws, dy_buf, st, *flag, use_ws, write_out,
                blockIdx.x - nbuild, gridDim.x - nbuild, threadIdx.x);
    }
}

// ---------------------------------------------------------------------------
extern "C" void kernel_launch(void* const* d_in, const int* in_sizes, int n_in,
                              void* d_out, int out_size, void* d_ws,
                              size_t ws_size, hipStream_t stream)
{
    const void* user_emb = d_in[0];
    const void* W_conv   = d_in[1];
    const void* b_conv   = d_in[2];
    const void* fus_w1   = d_in[3];
    const void* fus_b1   = d_in[4];
    const void* fus_w2   = d_in[5];
    const void* fus_b2   = d_in[6];
    const int* edge_nodes = (const int*)d_in[7];
    const int* edge_hyper = (const int*)d_in[8];

    const size_t ND = (size_t)N_USERS * DIM;

    // ws layout (fp32 word offsets) — R7-proven base (51.83 MB):
    //   0        : flag
    //   16       : st [8448]
    //   8464     : head_e int [50000]
    //   58464    : head_n int [100000]
    //   158464   : next_e int [800000]
    //   958464   : next_n int [800000]
    //   1758464  : e bf16 [E*D]
    //   3358464  : dy fp32 [N*D]
    //   9758464  : h bf16 [N*D]
    //   12958464 : optional fp32 carry [N*D] -> 77.43 MB
    float* ws = (float*)d_ws;
    int*   flag   = (int*)ws;
    float* st     = ws + 16;
    int*   head_e = (int*)(ws + 8464);
    int*   head_n = (int*)(ws + 58464);
    int*   next_e = (int*)(ws + 158464);
    int*   next_n = (int*)(ws + 958464);
    __hip_bfloat16* e_buf = (__hip_bfloat16*)(ws + 1758464);
    float* dy_buf = ws + 3358464;
    __hip_bfloat16* h = (__hip_bfloat16*)(ws + 9758464);
    float* carry_ws   = ws + 12958464;

    const size_t need_ws_carry = (12958464 + ND) * 4;
    const int use_ws = (ws_size >= need_ws_carry) ? 1 : 0;

    k_detect<<<1, 256, 0, stream>>>((const unsigned short*)user_emb, flag);
    k_convert_params<<<(8385 + 255) / 256, 256, 0, stream>>>(
        W_conv, b_conv, fus_w1, fus_b1, fus_w2, fus_b2, flag, st);

    // prologue: transform || build(0)  (tag 1)
    k_trans_build<<<TR_BLOCKS + B_BLOCKS, 256, 0, stream>>>(
        user_emb, flag, st, h, edge_nodes, edge_hyper,
        head_e, next_e, head_n, next_n, 1);

    for (int t = 0; t < T_STEPS; ++t) {
        const int* nodes  = edge_nodes + (size_t)t * NNZ_E;
        const int* hyper  = edge_hyper + (size_t)t * NNZ_E;
        const int* nodes1 = edge_nodes + (size_t)(t + 1) * NNZ_E;
        const int* hyper1 = edge_hyper + (size_t)(t + 1) * NNZ_E;
        int tag = t + 1;

        k_gather_e<<<GE_BLOCKS, 256, 0, stream>>>(
            h, nodes, head_e, next_e, e_buf, tag);
        k_gather_n<<<GN_BLOCKS, 256, 0, stream>>>(
            e_buf, hyper, head_n, next_n, dy_buf,
            d_out, carry_ws, flag, use_ws, (t == 0) ? 1 : 0, tag);

        // build(t+1) || fuse(t)   (t=0: build only; t=7: fuse only)
        int do_b  = (t < T_STEPS - 1) ? 1 : 0;
        int do_f  = (t > 0) ? 1 : 0;
        int nb    = do_b ? B_BLOCKS : 0;
        int grid  = nb + (do_f ? FU_BLOCKS : 0);
        k_build_fuse<<<grid, 256, 0, stream>>>(
            do_b ? nodes1 : nodes, do_b ? hyper1 : hyper,
            head_e, next_e, head_n, next_n, t + 2, nb,
            d_out, carry_ws, dy_buf, st, flag, use_ws, do_f,
            (t == T_STEPS - 1) ? 1 : 0);
    }
}